// Round 8
// baseline (435.560 us; speedup 1.0000x reference)
//
#include <hip/hip_runtime.h>
#include <hip/hip_bf16.h>
#include <cstdint>

#define CDIM 256
#define KNN  16
#define NCHUNK 196   // chunks; grid = 12 slices * NCHUNK = 2352 (2352%8==0)

typedef __attribute__((ext_vector_type(8))) __bf16 bf16x8;
typedef __attribute__((ext_vector_type(4))) float  f4;

__device__ inline ushort f2bf(float f) {
    __bf16 b = (__bf16)f;
    return __builtin_bit_cast(ushort, b);
}
__device__ inline float bf2f(ushort h) {
    return __builtin_bit_cast(float, (unsigned int)h << 16);
}
__device__ inline bf16x8 cvt8(f4 a, f4 b) {
    bf16x8 r;
    r[0] = (__bf16)a[0]; r[1] = (__bf16)a[1]; r[2] = (__bf16)a[2]; r[3] = (__bf16)a[3];
    r[4] = (__bf16)b[0]; r[5] = (__bf16)b[1]; r[6] = (__bf16)b[2]; r[7] = (__bf16)b[3];
    return r;
}

// Weight-in-LDS fused QKV projection, round 8: cross-group register
// double-buffer. Group g+1's 16-load burst issues BEFORE group g's compute
// (sched_barrier-pinned), so each burst has a full group-compute of latency
// cover; the compiler emits counted vmcnt waits (T4). K/V written to an
// interleaved [Krow|Vrow] 1KB record per point for attn gather locality.
__global__ __launch_bounds__(256, 2)
void proj_ldsw(const float* __restrict__ qf, const float* __restrict__ kvf,
               const float* __restrict__ Wq, const float* __restrict__ Wk,
               const float* __restrict__ Wv,
               const float* __restrict__ bq, const float* __restrict__ bk,
               const float* __restrict__ bv, const float* __restrict__ sens,
               float* __restrict__ Qout, ushort* __restrict__ KVout,
               int M, int Npts, int nwg, int ngroups)
{
    __shared__ ushort Wlds[64 * CDIM];   // 32 KB

    // m204 bijective XCD swizzle: the 12 slices of a chunk land on one XCD.
    const int orig = blockIdx.x;
    const int xcd = orig & 7, lin = orig >> 3;
    const int q8 = nwg >> 3, r8 = nwg & 7;
    const int wgid = (xcd < r8 ? xcd * (q8 + 1) : r8 * (q8 + 1) + (xcd - r8) * q8) + lin;
    const int chunk = wgid / 12, matws = wgid % 12;
    const int mat = matws >> 2, ws = matws & 3;

    const int tid  = threadIdx.x;
    const int lane = tid & 63;
    const int wid  = tid >> 6;
    const int l15  = lane & 15, l4 = lane >> 4;
    const int wbase = ws * 64;           // 64 output columns owned by this block

    const float* feat = (mat == 0) ? qf : kvf;
    const float* Wm   = (mat == 0) ? Wq : (mat == 1 ? Wk : Wv);
    const float* bias = (mat == 0) ? bq : (mat == 1 ? bk : bv);

    // ---- stage weight slice: 64 rows x 256 f32 -> bf16 LDS (swizzled) ----
    #pragma unroll
    for (int i = 0; i < 16; i++) {
        int idx = i * 256 + tid;          // f4 index, 4096 total (64 per row)
        int row = idx >> 6, c4 = idx & 63;
        float4 v = *(const float4*)(Wm + (size_t)(wbase + row) * CDIM + c4 * 4);
        ushort4 h;
        h.x = f2bf(v.x); h.y = f2bf(v.y); h.z = f2bf(v.z); h.w = f2bf(v.w);
        *(ushort4*)((char*)Wlds + row * 512 + ((c4 * 8) ^ ((row & 7) << 4))) = h;
    }
    __syncthreads();

    f4 biasf[4];
    #pragma unroll
    for (int mi = 0; mi < 4; mi++)
        biasf[mi] = *(const f4*)(bias + wbase + mi * 16 + l4 * 4);

    // clamped per-group load pointer (always in-bounds, uniform issue)
    auto ldptr = [&](int g) -> const float* {
        int m0 = g * 64 + wid * 16;
        if (g >= ngroups || m0 >= M) m0 = 0;
        return feat + (size_t)m0 * CDIM + (size_t)l15 * CDIM + l4 * 8;
    };
    auto issue = [&](const float* p, f4 (&A)[8], f4 (&B)[8]) {
        #pragma unroll
        for (int ks = 0; ks < 8; ks++) {
            A[ks] = *(const f4*)(p + ks * 32);
            B[ks] = *(const f4*)(p + ks * 32 + 4);
        }
    };
    auto compute = [&](int g, f4 (&A)[8], f4 (&B)[8]) {
        const int m0 = g * 64 + wid * 16;
        if (g >= ngroups || m0 >= M) return;

        f4 acc[4];
        #pragma unroll
        for (int mi = 0; mi < 4; mi++) acc[mi] = (f4){0.f, 0.f, 0.f, 0.f};

        #pragma unroll
        for (int ks = 0; ks < 8; ks++) {
            const bf16x8 af = cvt8(A[ks], B[ks]);
            #pragma unroll
            for (int mi = 0; mi < 4; mi++) {
                const int r = mi * 16 + l15;
                const bf16x8 wfr = *(const bf16x8*)((const char*)Wlds + r * 512
                                      + ((ks * 64 + l4 * 16) ^ ((r & 7) << 4)));
                acc[mi] = __builtin_amdgcn_mfma_f32_16x16x32_bf16(wfr, af, acc[mi], 0, 0, 0);
            }
        }

        // epilogue: D col(lane&15)=feature row m, row=l4*4+reg=W col
        const int m = m0 + l15;
        const int nidx = m >= Npts ? m - Npts : m;
        const float sw = (mat == 0) ? 1.f : sens[nidx];
        #pragma unroll
        for (int mi = 0; mi < 4; mi++) {
            const int wr0 = wbase + mi * 16 + l4 * 4;
            f4 v = acc[mi] + biasf[mi];
            if (mat == 0) {
                __builtin_nontemporal_store(v, (f4*)(Qout + (size_t)m * CDIM + wr0));
            } else {
                v *= sw;
                ushort4 h;
                h.x = f2bf(v[0]); h.y = f2bf(v[1]);
                h.z = f2bf(v[2]); h.w = f2bf(v[3]);
                // interleaved KV record: [Krow 512B | Vrow 512B] per point
                *(ushort4*)(KVout + (size_t)m * 512 + (mat == 2 ? 256 : 0) + wr0) = h;
            }
        }
    };

    f4 A0[8], B0[8], A1[8], B1[8];
    issue(ldptr(chunk), A0, B0);
    for (int g = chunk; g < ngroups; g += 2 * NCHUNK) {
        issue(ldptr(g + NCHUNK), A1, B1);
        __builtin_amdgcn_sched_barrier(0);
        compute(g, A0, B0);
        issue(ldptr(g + 2 * NCHUNK), A0, B0);
        __builtin_amdgcn_sched_barrier(0);
        compute(g + NCHUNK, A1, B1);
    }
}

// One wave per point: gathered 16-NN attention from interleaved KV records
// (K[j],V[j] = adjacent 512B halves of one 1KB record -> DRAM page locality).
__global__ __launch_bounds__(256, 4)
void attn_ln_bf(float* __restrict__ QO, const ushort* __restrict__ KV,
                const int* __restrict__ knn,
                const float* __restrict__ ln_g, const float* __restrict__ ln_b,
                int Ntot, int Npts)
{
    const int w = blockIdx.x * 4 + (threadIdx.x >> 6);
    if (w >= Ntot) return;
    const int lane = threadIdx.x & 63;
    const int n    = w >= Npts ? w - Npts : w;
    const int rb   = w >= Npts ? Npts : 0;      // record-base for this batch

    const f4 q = __builtin_nontemporal_load(
        (const f4*)(QO + (size_t)w * CDIM + lane * 4));

    const int ns = __builtin_amdgcn_readfirstlane(n);
    const int* ki = knn + ns * KNN;
    int idxs[KNN];
    #pragma unroll
    for (int j = 0; j < KNN; j++) idxs[j] = ki[j];

    // batched gathers, K/V adjacent per record
    ushort4 kr[KNN], vr[KNN];
    #pragma unroll
    for (int j = 0; j < KNN; j++) {
        const ushort* rec = KV + (size_t)(rb + idxs[j]) * 512;
        kr[j] = *(const ushort4*)(rec + lane * 4);
        vr[j] = *(const ushort4*)(rec + 256 + lane * 4);
    }

    float d[KNN];
    #pragma unroll
    for (int j = 0; j < KNN; j++)
        d[j] = q[0] * bf2f(kr[j].x) + q[1] * bf2f(kr[j].y)
             + q[2] * bf2f(kr[j].z) + q[3] * bf2f(kr[j].w);

    #pragma unroll
    for (int m = 1; m < 64; m <<= 1) {
        #pragma unroll
        for (int j = 0; j < KNN; j++) d[j] += __shfl_xor(d[j], m, 64);
    }

    float mx = -1e30f;
    #pragma unroll
    for (int j = 0; j < KNN; j++) { d[j] *= 0.0625f; mx = fmaxf(mx, d[j]); }
    float s = 0.f;
    #pragma unroll
    for (int j = 0; j < KNN; j++) { d[j] = __expf(d[j] - mx); s += d[j]; }
    const float inv = 1.f / s;

    f4 o = (f4){0.f, 0.f, 0.f, 0.f};
    #pragma unroll
    for (int j = 0; j < KNN; j++) {
        const float pj = d[j] * inv;
        o[0] += pj * bf2f(vr[j].x); o[1] += pj * bf2f(vr[j].y);
        o[2] += pj * bf2f(vr[j].z); o[3] += pj * bf2f(vr[j].w);
    }

    f4 x = o + q;

    float ssum = x[0] + x[1] + x[2] + x[3];
    #pragma unroll
    for (int m = 1; m < 64; m <<= 1) ssum += __shfl_xor(ssum, m, 64);
    const float mu = ssum * (1.f / 256.f);

    f4 e;
    e[0] = x[0] - mu; e[1] = x[1] - mu; e[2] = x[2] - mu; e[3] = x[3] - mu;
    float vsum = e[0] * e[0] + e[1] * e[1] + e[2] * e[2] + e[3] * e[3];
    #pragma unroll
    for (int m = 1; m < 64; m <<= 1) vsum += __shfl_xor(vsum, m, 64);
    const float rstd = rsqrtf(vsum * (1.f / 256.f) + 1e-5f);

    const f4 g  = *(const f4*)(ln_g + lane * 4);
    const f4 bb = *(const f4*)(ln_b + lane * 4);
    f4 outv;
    outv[0] = e[0] * rstd * g[0] + bb[0];
    outv[1] = e[1] * rstd * g[1] + bb[1];
    outv[2] = e[2] * rstd * g[2] + bb[2];
    outv[3] = e[3] * rstd * g[3] + bb[3];
    __builtin_nontemporal_store(outv, (f4*)(QO + (size_t)w * CDIM + lane * 4));
}

extern "C" void kernel_launch(void* const* d_in, const int* in_sizes, int n_in,
                              void* d_out, int out_size, void* d_ws, size_t ws_size,
                              hipStream_t stream)
{
    const float* q_feat  = (const float*)d_in[0];
    const float* kv_feat = (const float*)d_in[1];
    const int*   knn     = (const int*)d_in[2];
    const float* sens    = (const float*)d_in[3];
    const float* Wq_w    = (const float*)d_in[4];
    const float* Wq_b    = (const float*)d_in[5];
    const float* Wk_w    = (const float*)d_in[6];
    const float* Wk_b    = (const float*)d_in[7];
    const float* Wv_w    = (const float*)d_in[8];
    const float* Wv_b    = (const float*)d_in[9];
    const float* ln_g    = (const float*)d_in[10];
    const float* ln_b    = (const float*)d_in[11];

    const int Npts = in_sizes[3];              // N = 50000
    const int M    = in_sizes[0] / CDIM;       // B*N = 100000
    const int ngroups = (M + 63) / 64;         // 1563

    ushort* KVtb = (ushort*)d_ws;              // [M] records of 1KB

    const int nwg = 12 * NCHUNK;               // 2352 blocks
    proj_ldsw<<<nwg, 256, 0, stream>>>(q_feat, kv_feat, Wq_w, Wk_w, Wv_w,
                                       Wq_b, Wk_b, Wv_b, sens,
                                       (float*)d_out, KVtb,
                                       M, Npts, nwg, ngroups);

    attn_ln_bf<<<(M + 3) / 4, 256, 0, stream>>>((float*)d_out, KVtb, knn,
                                                ln_g, ln_b, M, Npts);
}